// Round 4
// baseline (621.219 us; speedup 1.0000x reference)
//
#include <hip/hip_runtime.h>
#include <hip/hip_bf16.h>
#include <math.h>

#define B_ 2
#define L_ 1024
#define DM 1024
#define DIN 2048
#define DS 16
#define DTR 64
#define NCH 16      // chunks per sequence
#define CHL 64      // chunk length

typedef __attribute__((ext_vector_type(8))) short bf16x8;
typedef __attribute__((ext_vector_type(4))) float f32x4;
typedef unsigned short ushort_t;
typedef unsigned int uint_t;

__device__ __forceinline__ float sigmoidf_(float x) { return 1.f / (1.f + __expf(-x)); }
__device__ __forceinline__ ushort_t f2b(float f) {
    uint_t b = __float_as_uint(f);
    return (ushort_t)((b + 0x7FFFu + ((b >> 16) & 1u)) >> 16);
}
__device__ __forceinline__ float b2f(ushort_t u) {
    return __uint_as_float(((uint_t)u) << 16);
}

// f32 -> bf16 (RTN) elementwise
__global__ __launch_bounds__(256) void f2b_k(const float* __restrict__ in,
                                             ushort_t* __restrict__ out, int n)
{
    int i = blockIdx.x * 256 + threadIdx.x;
    if (i < n) out[i] = f2b(in[i]);
}

// ---------------- MFMA GEMM: C[M,N] = A[M,K] * Bt[N,K]^T (bf16 in, f32 acc) ----
// EPI: 0 = f32 C; 1 = f32 C + bf16 Cb; 2 = bf16 Cb = softplus(C + bias[n]);
//      3 = bf16 only; 4 = f32 C = acc + res
template<int EPI>
__global__ __launch_bounds__(256) void mgemm(const ushort_t* __restrict__ A,
    const ushort_t* __restrict__ Bt, float* __restrict__ Cf, ushort_t* __restrict__ Cb,
    const float* __restrict__ bias, const float* __restrict__ res,
    int M, int N, int K, int lda, int ldb)
{
    __shared__ ushort_t sA[128 * 32];
    __shared__ ushort_t sB[128 * 32];
    const int tid = threadIdx.x;
    const int lane = tid & 63, wv = tid >> 6;
    const int wm = wv >> 1, wn = wv & 1;
    const int m0 = blockIdx.y * 128, n0 = blockIdx.x * 128;
    const int sr = tid >> 2;            // 0..63
    const int sc = (tid & 3) * 8;       // 0,8,16,24
    f32x4 acc[4][4] = {};

    for (int k0 = 0; k0 < K; k0 += 32) {
#pragma unroll
        for (int j = 0; j < 2; ++j) {
            int ra = sr + j * 64;
            int ga = m0 + ra;
            __builtin_amdgcn_global_load_lds(
                (const uint_t*)(A + (size_t)ga * lda + k0 + sc),
                (uint_t*)(sA + ra * 32 + sc), 16, 0, 0);
            int gb = n0 + ra; if (gb >= N) gb = N - 1;   // clamp (N=96 case)
            __builtin_amdgcn_global_load_lds(
                (const uint_t*)(Bt + (size_t)gb * ldb + k0 + sc),
                (uint_t*)(sB + ra * 32 + sc), 16, 0, 0);
        }
        __syncthreads();
        bf16x8 af[4], bfr[4];
#pragma unroll
        for (int i = 0; i < 4; ++i) {
            af[i]  = *(const bf16x8*)(sA + (wm * 64 + i * 16 + (lane & 15)) * 32 + (lane >> 4) * 8);
            bfr[i] = *(const bf16x8*)(sB + (wn * 64 + i * 16 + (lane & 15)) * 32 + (lane >> 4) * 8);
        }
#pragma unroll
        for (int i = 0; i < 4; ++i)
#pragma unroll
            for (int jj = 0; jj < 4; ++jj)
                acc[i][jj] = __builtin_amdgcn_mfma_f32_16x16x32_bf16(af[i], bfr[jj], acc[i][jj], 0, 0, 0);
        __syncthreads();
    }

    const int cr = (lane >> 4) * 4, cc = lane & 15;
#pragma unroll
    for (int i = 0; i < 4; ++i) {
        int mrow = m0 + wm * 64 + i * 16 + cr;
#pragma unroll
        for (int jj = 0; jj < 4; ++jj) {
            int ncol = n0 + wn * 64 + jj * 16 + cc;
            if (ncol < N) {
#pragma unroll
                for (int r = 0; r < 4; ++r) {
                    float v = acc[i][jj][r];
                    size_t off = (size_t)(mrow + r) * N + ncol;
                    if (EPI == 0) { Cf[off] = v; }
                    else if (EPI == 1) { Cf[off] = v; Cb[off] = f2b(v); }
                    else if (EPI == 2) {
                        float s = v + bias[ncol];
                        Cb[off] = f2b((s > 20.f) ? s : log1pf(expf(s)));
                    }
                    else if (EPI == 3) { Cb[off] = f2b(v); }
                    else { Cf[off] = v + res[off]; }
                }
            }
        }
    }
}

// conv + silu: reads bf16 xz (u half), writes f32 uc and bf16 ucb
__global__ __launch_bounds__(256) void conv_silu_k(const ushort_t* __restrict__ xzb,
    const float* __restrict__ cw, const float* __restrict__ cb,
    float* __restrict__ uc, ushort_t* __restrict__ ucb)
{
    int idx = blockIdx.x * 256 + threadIdx.x;   // over B*L*DIN
    int d = idx & (DIN - 1);
    int t = (idx >> 11) & (L_ - 1);
    int b = idx >> 21;
    const ushort_t* base = xzb + (size_t)b * L_ * (2 * DIN) + d;
    float acc = cb[d];
#pragma unroll
    for (int j = 0; j < 4; ++j) {
        int tt = t - 3 + j;
        if (tt >= 0) acc = fmaf(cw[d * 4 + j], b2f(base[(size_t)tt * (2 * DIN)]), acc);
    }
    float v = acc * sigmoidf_(acc);
    uc[idx] = v;
    ucb[idx] = f2b(v);
}

// ---------------- chunk-parallel selective scan ------------------------------
// S1: per (b, dgrp16, chunk): local scan from zero -> q_end[n], s_end (=sum dt)
__global__ __launch_bounds__(256) void scan_s1(const ushort_t* __restrict__ dtfb,
    const float* __restrict__ uc, const float* __restrict__ xdbl,
    const float* __restrict__ A_log,
    float* __restrict__ bnd_q, float* __restrict__ bnd_s)
{
    __shared__ float sdt[CHL * 16];
    __shared__ float su[CHL * 16];
    __shared__ float sB[CHL * 16];
    const int tid = threadIdx.x;
    const int g = tid >> 4, n = tid & 15;
    const int bx = blockIdx.x;
    const int c = bx & 15;
    const int dgrp = (bx >> 4) & 127;
    const int b = bx >> 11;
    const int dbase = dgrp << 4;
    const int t0 = c * CHL;
    const float A_dn = -__expf(A_log[(size_t)(dbase + g) * DS + n]);

#pragma unroll
    for (int k = 0; k < 4; ++k) {
        int idx = tid + k * 256; int i = idx >> 4, jj = idx & 15;
        size_t off = (size_t)(b * L_ + t0 + i) * DIN + dbase + jj;
        sdt[idx] = b2f(dtfb[off]);
        su[idx] = uc[off];
        sB[idx] = xdbl[(size_t)(b * L_ + t0 + i) * 96 + 64 + jj];
    }
    __syncthreads();
    float q = 0.f, s = 0.f;
#pragma unroll 8
    for (int i = 0; i < CHL; ++i) {
        float dtv = sdt[i * 16 + g];
        float uv  = su[i * 16 + g];
        float Bv  = sB[i * 16 + n];
        float dA  = __expf(dtv * A_dn);
        q = fmaf(dA, q, dtv * Bv * uv);
        s += dtv;
    }
    bnd_q[(size_t)bx * 256 + tid] = q;
    if (n == 0) bnd_s[(size_t)bx * 16 + g] = s;
}

// S2: per (b, dgrp16, chunk): combine boundaries -> H_{c-1}, rescan chunk,
// deferred n-reduce, gate with silu(z), write bf16 ucb.
__global__ __launch_bounds__(256) void scan_s2(const ushort_t* __restrict__ dtfb,
    const float* __restrict__ uc, const float* __restrict__ xdbl,
    const ushort_t* __restrict__ xzb, const float* __restrict__ A_log,
    const float* __restrict__ Dvec, const float* __restrict__ bnd_q,
    const float* __restrict__ bnd_s, ushort_t* __restrict__ ucb)
{
    __shared__ float sBC[CHL * 32];       // [t][32] B then C
    __shared__ float sdt[CHL * 16];       // [t][g]
    __shared__ float suT[16 * 65];        // [g][t] padded
    __shared__ ushort_t sy[CHL * 257];    // [t][tid] p-values, bf16
    __shared__ float sy3[CHL * 17];       // [t][g] reduced y
    __shared__ float sD[16];
    const int tid = threadIdx.x;
    const int lane = tid & 63, wave = tid >> 6;
    const int g = tid >> 4, n = tid & 15;
    const int bx = blockIdx.x;
    const int c = bx & 15;
    const int dgrp = (bx >> 4) & 127;
    const int b = bx >> 11;
    const int dbase = dgrp << 4;
    const int t0 = c * CHL;
    const float A_dn = -__expf(A_log[(size_t)(dbase + g) * DS + n]);
    if (tid < 16) sD[tid] = Dvec[dbase + tid];

    // stage chunk inputs
#pragma unroll
    for (int j = 0; j < 8; ++j) {
        int idx = tid + j * 256; int i = idx >> 5, jj = idx & 31;
        sBC[idx] = xdbl[(size_t)(b * L_ + t0 + i) * 96 + 64 + jj];
    }
#pragma unroll
    for (int j = 0; j < 4; ++j) {
        int idx = tid + j * 256; int i = idx >> 4, jj = idx & 15;
        size_t off = (size_t)(b * L_ + t0 + i) * DIN + dbase + jj;
        sdt[idx] = b2f(dtfb[off]);
        suT[jj * 65 + i] = uc[off];
    }

    // boundary combine: H_{c-1} for this lane's (g, n)
    float hs = 0.f;
    const size_t base_bx = (size_t)(b * 2048 + dgrp * 16);
    for (int cc = 0; cc < c; ++cc) {
        float qv = bnd_q[(base_bx + cc) * 256 + tid];
        float sv = bnd_s[(base_bx + cc) * 16 + g];
        hs = fmaf(__expf(A_dn * sv), hs, qv);
    }
    __syncthreads();

    // serial chunk scan; p-values deferred to LDS (bf16)
#pragma unroll 8
    for (int i = 0; i < CHL; ++i) {
        float dtv = sdt[i * 16 + g];
        float uv  = suT[g * 65 + i];
        float Bv  = sBC[i * 32 + n];
        float Cv  = sBC[i * 32 + 16 + n];
        float dA  = __expf(dtv * A_dn);
        hs = fmaf(dA, hs, dtv * Bv * uv);
        sy[i * 257 + tid] = f2b(hs * Cv);
    }
    __syncthreads();
    // reduce over n: thread (wave,lane) handles (t=lane, ch=wave+4k)
#pragma unroll
    for (int k = 0; k < 4; ++k) {
        int g2 = wave + 4 * k;
        float sum = 0.f;
#pragma unroll
        for (int nn = 0; nn < 16; ++nn) sum += b2f(sy[lane * 257 + g2 * 16 + nn]);
        float uv = suT[g2 * 65 + lane];
        sy3[lane * 17 + g2] = fmaf(uv, sD[g2], sum);
    }
    __syncthreads();
    // gated coalesced store
#pragma unroll
    for (int k = 0; k < 4; ++k) {
        int idx = tid + k * 256; int row = idx >> 4, col = idx & 15;
        float y = sy3[row * 17 + col];
        float z = b2f(xzb[(size_t)(b * L_ + t0 + row) * (2 * DIN) + DIN + dbase + col]);
        y *= z * sigmoidf_(z);
        ucb[(size_t)(b * L_ + t0 + row) * DIN + dbase + col] = f2b(y);
    }
}

extern "C" void kernel_launch(void* const* d_in, const int* in_sizes, int n_in,
                              void* d_out, int out_size, void* d_ws, size_t ws_size,
                              hipStream_t stream)
{
    (void)in_sizes; (void)n_in; (void)out_size; (void)ws_size;
    const float* x      = (const float*)d_in[0];
    const float* W_in   = (const float*)d_in[1];
    const float* conv_w = (const float*)d_in[2];
    const float* conv_b = (const float*)d_in[3];
    const float* W_x    = (const float*)d_in[4];
    const float* W_dt   = (const float*)d_in[5];
    const float* b_dt   = (const float*)d_in[6];
    const float* A_log  = (const float*)d_in[7];
    const float* Dv     = (const float*)d_in[8];
    const float* W_out  = (const float*)d_in[9];
    float* out = (float*)d_out;

    // workspace layout (f32 region then u16 region)
    float* uc      = (float*)d_ws;                       // 4,194,304 f32
    float* xdbl    = uc + 4194304;                       //   196,608 f32
    float* bnd_q   = xdbl + 196608;                      // 1,048,576 f32
    float* bnd_s   = bnd_q + 1048576;                    //    65,536 f32
    ushort_t* dtfb = (ushort_t*)(bnd_s + 65536);         // 4,194,304 u16
    ushort_t* xzb  = dtfb + 4194304;                     // 8,388,608
    ushort_t* ucb  = xzb + 8388608;                      // 4,194,304
    ushort_t* xdblb= ucb + 4194304;                      //   196,608
    ushort_t* xb   = xdblb + 196608;                     // 2,097,152 (x/h bf16)
    ushort_t* wib  = xb + 2097152;                       // 8,388,608
    ushort_t* wxb  = wib + 8388608;                      //   393,216
    ushort_t* wdb  = wxb + 393216;                       //   262,144
    ushort_t* wob  = wdb + 262144;                       // 4,194,304

    const int M = B_ * L_;
    // converts
    f2b_k<<<2097152 / 256, 256, 0, stream>>>(x, xb, 2097152);
    f2b_k<<<8388608 / 256, 256, 0, stream>>>(W_in, wib, 8388608);
    f2b_k<<<(393216 + 255) / 256, 256, 0, stream>>>(W_x, wxb, 393216);
    f2b_k<<<(262144 + 255) / 256, 256, 0, stream>>>(W_dt, wdb, 262144);
    f2b_k<<<4194304 / 256, 256, 0, stream>>>(W_out, wob, 4194304);

    for (int layer = 0; layer < 2; ++layer) {
        // xzb = bf16( h @ W_in^T )  [M, 4096]
        mgemm<3><<<dim3(4096 / 128, M / 128), 256, 0, stream>>>(
            xb, wib + (size_t)layer * 4194304, nullptr, xzb, nullptr, nullptr,
            M, 2 * DIN, DM, DM, DM);
        // uc/ucb = silu(conv(u) + b)
        conv_silu_k<<<(B_ * L_ * DIN) / 256, 256, 0, stream>>>(
            xzb, conv_w + (size_t)layer * DIN * 4, conv_b + (size_t)layer * DIN, uc, ucb);
        // xdbl (f32 + bf16) = uc @ W_x^T  [M, 96]
        mgemm<1><<<dim3(1, M / 128), 256, 0, stream>>>(
            ucb, wxb + (size_t)layer * 196608, xdbl, xdblb, nullptr, nullptr,
            M, 96, DIN, DIN, DIN);
        // dtfb = bf16(softplus(xdblb[:, :64] @ W_dt^T + b_dt))  [M, 2048]
        mgemm<2><<<dim3(2048 / 128, M / 128), 256, 0, stream>>>(
            xdblb, wdb + (size_t)layer * 131072, nullptr, dtfb,
            b_dt + (size_t)layer * DIN, nullptr, M, DIN, DTR, 96, DTR);
        // chunk-parallel scan
        scan_s1<<<4096, 256, 0, stream>>>(dtfb, uc, xdbl,
            A_log + (size_t)layer * DIN * DS, bnd_q, bnd_s);
        scan_s2<<<4096, 256, 0, stream>>>(dtfb, uc, xdbl, xzb,
            A_log + (size_t)layer * DIN * DS, Dv + (size_t)layer * DIN,
            bnd_q, bnd_s, ucb);
        // out-proj: layer0 -> xb (bf16 h); layer1 -> out = acc + x
        if (layer == 0)
            mgemm<3><<<dim3(1024 / 128, M / 128), 256, 0, stream>>>(
                ucb, wob + (size_t)layer * 2097152, nullptr, xb, nullptr, nullptr,
                M, DM, DIN, DIN, DIN);
        else
            mgemm<4><<<dim3(1024 / 128, M / 128), 256, 0, stream>>>(
                ucb, wob + (size_t)layer * 2097152, out, nullptr, nullptr, x,
                M, DM, DIN, DIN, DIN);
    }
}

// Round 5
// 494.563 us; speedup vs baseline: 1.2561x; 1.2561x over previous
//
#include <hip/hip_runtime.h>
#include <hip/hip_bf16.h>
#include <math.h>

#define B_ 2
#define L_ 1024
#define DM 1024
#define DIN 2048
#define DS 16
#define DTR 64
#define CHL 64      // chunk length

typedef __attribute__((ext_vector_type(8))) short bf16x8;
typedef __attribute__((ext_vector_type(8))) unsigned short u16x8;
typedef __attribute__((ext_vector_type(4))) float f32x4;
typedef unsigned short ushort_t;
typedef unsigned int uint_t;

__device__ __forceinline__ float sigmoidf_(float x) { return 1.f / (1.f + __expf(-x)); }
__device__ __forceinline__ ushort_t f2b(float f) {
    uint_t b = __float_as_uint(f);
    return (ushort_t)((b + 0x7FFFu + ((b >> 16) & 1u)) >> 16);
}
__device__ __forceinline__ float b2f(ushort_t u) {
    return __uint_as_float(((uint_t)u) << 16);
}
// DPP row-rotate add: x + ror_within_row16(x, N); pure VALU, no LDS pipe
template<int CTRL>
__device__ __forceinline__ float rradd(float x) {
    int y = __builtin_amdgcn_update_dpp(0, __float_as_int(x), CTRL, 0xf, 0xf, true);
    return x + __int_as_float(y);
}

// f32 -> bf16 (RTN) elementwise
__global__ __launch_bounds__(256) void f2b_k(const float* __restrict__ in,
                                             ushort_t* __restrict__ out, int n)
{
    int i = blockIdx.x * 256 + threadIdx.x;
    if (i < n) out[i] = f2b(in[i]);
}

// ---------------- MFMA GEMM 128x128: C = A[M,K] * Bt[N,K]^T --------------------
// EPI: 2 = bf16 Cb = softplus(C + bias[n]); 3 = bf16 only
template<int EPI>
__global__ __launch_bounds__(256) void mgemm(const ushort_t* __restrict__ A,
    const ushort_t* __restrict__ Bt, float* __restrict__ Cf, ushort_t* __restrict__ Cb,
    const float* __restrict__ bias, const float* __restrict__ res,
    int M, int N, int K, int lda, int ldb)
{
    __shared__ ushort_t sA[128 * 32];
    __shared__ ushort_t sB[128 * 32];
    const int tid = threadIdx.x;
    const int lane = tid & 63, wv = tid >> 6;
    const int wm = wv >> 1, wn = wv & 1;
    const int m0 = blockIdx.y * 128, n0 = blockIdx.x * 128;
    const int sr = tid >> 2;
    const int sc = (tid & 3) * 8;
    f32x4 acc[4][4] = {};

    for (int k0 = 0; k0 < K; k0 += 32) {
#pragma unroll
        for (int j = 0; j < 2; ++j) {
            int ra = sr + j * 64;
            int ga = m0 + ra;
            __builtin_amdgcn_global_load_lds(
                (const uint_t*)(A + (size_t)ga * lda + k0 + sc),
                (uint_t*)(sA + ra * 32 + sc), 16, 0, 0);
            int gb = n0 + ra; if (gb >= N) gb = N - 1;
            __builtin_amdgcn_global_load_lds(
                (const uint_t*)(Bt + (size_t)gb * ldb + k0 + sc),
                (uint_t*)(sB + ra * 32 + sc), 16, 0, 0);
        }
        __syncthreads();
        bf16x8 af[4], bfr[4];
#pragma unroll
        for (int i = 0; i < 4; ++i) {
            af[i]  = *(const bf16x8*)(sA + (wm * 64 + i * 16 + (lane & 15)) * 32 + (lane >> 4) * 8);
            bfr[i] = *(const bf16x8*)(sB + (wn * 64 + i * 16 + (lane & 15)) * 32 + (lane >> 4) * 8);
        }
#pragma unroll
        for (int i = 0; i < 4; ++i)
#pragma unroll
            for (int jj = 0; jj < 4; ++jj)
                acc[i][jj] = __builtin_amdgcn_mfma_f32_16x16x32_bf16(af[i], bfr[jj], acc[i][jj], 0, 0, 0);
        __syncthreads();
    }

    const int cr = (lane >> 4) * 4, cc = lane & 15;
#pragma unroll
    for (int i = 0; i < 4; ++i) {
        int mrow = m0 + wm * 64 + i * 16 + cr;
#pragma unroll
        for (int jj = 0; jj < 4; ++jj) {
            int ncol = n0 + wn * 64 + jj * 16 + cc;
            if (ncol < N) {
#pragma unroll
                for (int r = 0; r < 4; ++r) {
                    float v = acc[i][jj][r];
                    size_t off = (size_t)(mrow + r) * N + ncol;
                    if (EPI == 2) {
                        float s = v + bias[ncol];
                        Cb[off] = f2b((s > 20.f) ? s : log1pf(expf(s)));
                    }
                    else { Cb[off] = f2b(v); }
                }
            }
        }
    }
    (void)Cf; (void)res;
}

// ---------------- MFMA GEMM 128xK split-K (for N=96 W_x proj) ------------------
// grid (1, M/128, KS); partial f32 out at pitch 96
__global__ __launch_bounds__(256) void mgemm_sk(const ushort_t* __restrict__ A,
    const ushort_t* __restrict__ Bt, float* __restrict__ P,
    int M, int N, int Kslice, int lda, int ldb)
{
    __shared__ ushort_t sA[128 * 32];
    __shared__ ushort_t sB[128 * 32];
    const int tid = threadIdx.x;
    const int lane = tid & 63, wv = tid >> 6;
    const int wm = wv >> 1, wn = wv & 1;
    const int m0 = blockIdx.y * 128;
    const int kbase = blockIdx.z * Kslice;
    const int sr = tid >> 2;
    const int sc = (tid & 3) * 8;
    f32x4 acc[4][4] = {};

    for (int k0 = kbase; k0 < kbase + Kslice; k0 += 32) {
#pragma unroll
        for (int j = 0; j < 2; ++j) {
            int ra = sr + j * 64;
            __builtin_amdgcn_global_load_lds(
                (const uint_t*)(A + (size_t)(m0 + ra) * lda + k0 + sc),
                (uint_t*)(sA + ra * 32 + sc), 16, 0, 0);
            int gb = ra; if (gb >= N) gb = N - 1;
            __builtin_amdgcn_global_load_lds(
                (const uint_t*)(Bt + (size_t)gb * ldb + k0 + sc),
                (uint_t*)(sB + ra * 32 + sc), 16, 0, 0);
        }
        __syncthreads();
        bf16x8 af[4], bfr[4];
#pragma unroll
        for (int i = 0; i < 4; ++i) {
            af[i]  = *(const bf16x8*)(sA + (wm * 64 + i * 16 + (lane & 15)) * 32 + (lane >> 4) * 8);
            bfr[i] = *(const bf16x8*)(sB + (wn * 64 + i * 16 + (lane & 15)) * 32 + (lane >> 4) * 8);
        }
#pragma unroll
        for (int i = 0; i < 4; ++i)
#pragma unroll
            for (int jj = 0; jj < 4; ++jj)
                acc[i][jj] = __builtin_amdgcn_mfma_f32_16x16x32_bf16(af[i], bfr[jj], acc[i][jj], 0, 0, 0);
        __syncthreads();
    }

    const int cr = (lane >> 4) * 4, cc = lane & 15;
    float* Pz = P + (size_t)blockIdx.z * M * 96;
#pragma unroll
    for (int i = 0; i < 4; ++i) {
        int mrow = m0 + wm * 64 + i * 16 + cr;
#pragma unroll
        for (int jj = 0; jj < 4; ++jj) {
            int ncol = wn * 64 + jj * 16 + cc;
            if (ncol < 96) {
#pragma unroll
                for (int r = 0; r < 4; ++r)
                    Pz[(size_t)(mrow + r) * 96 + ncol] = acc[i][jj][r];
            }
        }
    }
}

// reduce split-K partials -> xdbl f32 + xdblb bf16
__global__ __launch_bounds__(256) void wxred_k(const float* __restrict__ P,
    float* __restrict__ xdbl, ushort_t* __restrict__ xdblb)
{
    int idx = blockIdx.x * 256 + threadIdx.x;   // < 2048*96
    float s = 0.f;
#pragma unroll
    for (int z = 0; z < 8; ++z) s += P[(size_t)z * 196608 + idx];
    xdbl[idx] = s;
    xdblb[idx] = f2b(s);
}

// ---------------- MFMA GEMM 128x64 (for N=1024 out-proj) -----------------------
// EPI: 3 = bf16 only; 4 = f32 C = acc + res
template<int EPI>
__global__ __launch_bounds__(256) void mgemm_n64(const ushort_t* __restrict__ A,
    const ushort_t* __restrict__ Bt, float* __restrict__ Cf, ushort_t* __restrict__ Cb,
    const float* __restrict__ res, int M, int N, int K, int lda, int ldb)
{
    __shared__ ushort_t sA[128 * 32];
    __shared__ ushort_t sB[64 * 32];
    const int tid = threadIdx.x;
    const int lane = tid & 63, wv = tid >> 6;
    const int m0 = blockIdx.y * 128, n0 = blockIdx.x * 64;
    const int sr = tid >> 2;
    const int sc = (tid & 3) * 8;
    f32x4 acc[2][4] = {};

    for (int k0 = 0; k0 < K; k0 += 32) {
#pragma unroll
        for (int j = 0; j < 2; ++j) {
            int ra = sr + j * 64;
            __builtin_amdgcn_global_load_lds(
                (const uint_t*)(A + (size_t)(m0 + ra) * lda + k0 + sc),
                (uint_t*)(sA + ra * 32 + sc), 16, 0, 0);
        }
        __builtin_amdgcn_global_load_lds(
            (const uint_t*)(Bt + (size_t)(n0 + sr) * ldb + k0 + sc),
            (uint_t*)(sB + sr * 32 + sc), 16, 0, 0);
        __syncthreads();
        bf16x8 af[2], bfr[4];
#pragma unroll
        for (int i = 0; i < 2; ++i)
            af[i]  = *(const bf16x8*)(sA + (wv * 32 + i * 16 + (lane & 15)) * 32 + (lane >> 4) * 8);
#pragma unroll
        for (int jj = 0; jj < 4; ++jj)
            bfr[jj] = *(const bf16x8*)(sB + (jj * 16 + (lane & 15)) * 32 + (lane >> 4) * 8);
#pragma unroll
        for (int i = 0; i < 2; ++i)
#pragma unroll
            for (int jj = 0; jj < 4; ++jj)
                acc[i][jj] = __builtin_amdgcn_mfma_f32_16x16x32_bf16(af[i], bfr[jj], acc[i][jj], 0, 0, 0);
        __syncthreads();
    }

    const int cr = (lane >> 4) * 4, cc = lane & 15;
#pragma unroll
    for (int i = 0; i < 2; ++i) {
        int mrow = m0 + wv * 32 + i * 16 + cr;
#pragma unroll
        for (int jj = 0; jj < 4; ++jj) {
            int ncol = n0 + jj * 16 + cc;
#pragma unroll
            for (int r = 0; r < 4; ++r) {
                float v = acc[i][jj][r];
                size_t off = (size_t)(mrow + r) * N + ncol;
                if (EPI == 3) Cb[off] = f2b(v);
                else Cf[off] = v + res[off];
            }
        }
    }
}

// conv + silu, 8 channels per thread (vectorized)
__global__ __launch_bounds__(256) void conv8_k(const ushort_t* __restrict__ xzb,
    const float* __restrict__ cw, const float* __restrict__ cb,
    float* __restrict__ uc, ushort_t* __restrict__ ucb)
{
    int idx8 = blockIdx.x * 256 + threadIdx.x;      // over B*L*DIN/8
    int d8 = (idx8 & 255) * 8;
    int t = (idx8 >> 8) & (L_ - 1);
    int b = idx8 >> 18;
    const ushort_t* base = xzb + (size_t)b * L_ * (2 * DIN) + d8;
    float acc[8];
    const float4* cb4 = (const float4*)(cb + d8);
    float4 cbl = cb4[0], cbh = cb4[1];
#pragma unroll
    for (int e = 0; e < 4; ++e) { acc[e] = ((const float*)&cbl)[e]; acc[4 + e] = ((const float*)&cbh)[e]; }
    float4 cwv[8];
#pragma unroll
    for (int e = 0; e < 8; ++e) cwv[e] = ((const float4*)cw)[d8 + e];
#pragma unroll
    for (int j = 0; j < 4; ++j) {
        int tt = t - 3 + j;
        if (tt >= 0) {
            u16x8 row = *(const u16x8*)(base + (size_t)tt * (2 * DIN));
#pragma unroll
            for (int e = 0; e < 8; ++e)
                acc[e] = fmaf(((const float*)&cwv[e])[j], b2f(row[e]), acc[e]);
        }
    }
    size_t off = (size_t)idx8 * 8;
    u16x8 ob;
#pragma unroll
    for (int e = 0; e < 8; ++e) {
        float v = acc[e] * sigmoidf_(acc[e]);
        uc[off + e] = v;
        ob[e] = f2b(v);
    }
    *(u16x8*)(ucb + off) = ob;
}

// ---------------- chunk-parallel selective scan ------------------------------
// S1: per (b, dgrp16, chunk): local scan from zero -> q_end[n], s_end (=sum dt)
__global__ __launch_bounds__(256) void scan_s1(const ushort_t* __restrict__ dtfb,
    const float* __restrict__ uc, const float* __restrict__ xdbl,
    const float* __restrict__ A_log,
    float* __restrict__ bnd_q, float* __restrict__ bnd_s)
{
    __shared__ uint_t sdtp[CHL * 16];    // {dt.bf16, (dt*u).bf16}
    __shared__ float sB[CHL * 16];
    const int tid = threadIdx.x;
    const int g = tid >> 4, n = tid & 15;
    const int bx = blockIdx.x;
    const int c = bx & 15;
    const int dgrp = (bx >> 4) & 127;
    const int b = bx >> 11;
    const int dbase = dgrp << 4;
    const int t0 = c * CHL;
    const float A_dn = -__expf(A_log[(size_t)(dbase + g) * DS + n]);

#pragma unroll
    for (int k = 0; k < 4; ++k) {
        int idx = tid + k * 256; int i = idx >> 4, jj = idx & 15;
        size_t off = (size_t)(b * L_ + t0 + i) * DIN + dbase + jj;
        ushort_t dtb = dtfb[off];
        float uv = uc[off];
        sdtp[idx] = (uint_t)dtb | ((uint_t)f2b(b2f(dtb) * uv) << 16);
        sB[idx] = xdbl[(size_t)(b * L_ + t0 + i) * 96 + 64 + jj];
    }
    __syncthreads();
    float q = 0.f, s = 0.f;
#pragma unroll 8
    for (int i = 0; i < CHL; ++i) {
        uint_t dp = sdtp[i * 16 + g];
        float dtv = __uint_as_float(dp << 16);
        float dtu = __uint_as_float(dp & 0xffff0000u);
        float Bv  = sB[i * 16 + n];
        float dA  = __expf(dtv * A_dn);
        q = fmaf(dA, q, dtu * Bv);
        s += dtv;
    }
    bnd_q[(size_t)bx * 256 + tid] = q;
    if (n == 0) bnd_s[(size_t)bx * 16 + g] = s;
}

// S2: combine boundaries -> H_{c-1}, rescan chunk with in-loop DPP n-reduce,
// gate with silu(z), write bf16 ucb.
__global__ __launch_bounds__(256) void scan_s2(const ushort_t* __restrict__ dtfb,
    const float* __restrict__ uc, const float* __restrict__ xdbl,
    const ushort_t* __restrict__ xzb, const float* __restrict__ A_log,
    const float* __restrict__ Dvec, const float* __restrict__ bnd_q,
    const float* __restrict__ bnd_s, ushort_t* __restrict__ ucb)
{
    __shared__ float sBCi[CHL * 32];     // [t][n][2] interleaved {B,C}
    __shared__ uint_t sdtp[CHL * 16];    // {dt.bf16, (dt*u).bf16}
    __shared__ float suT[16 * 65];       // [g][t] padded (for D-term)
    __shared__ float sy3[CHL * 17];      // [t][g] reduced y
    __shared__ float sD[16];
    const int tid = threadIdx.x;
    const int g = tid >> 4, n = tid & 15;
    const int bx = blockIdx.x;
    const int c = bx & 15;
    const int dgrp = (bx >> 4) & 127;
    const int b = bx >> 11;
    const int dbase = dgrp << 4;
    const int t0 = c * CHL;
    const float A_dn = -__expf(A_log[(size_t)(dbase + g) * DS + n]);
    if (tid < 16) sD[tid] = Dvec[dbase + tid];

    // stage chunk inputs
#pragma unroll
    for (int j = 0; j < 4; ++j) {
        int idx = tid + j * 256; int i = idx >> 4, jj = idx & 15;
        size_t row = (size_t)(b * L_ + t0 + i);
        sBCi[i * 32 + jj * 2]     = xdbl[row * 96 + 64 + jj];
        sBCi[i * 32 + jj * 2 + 1] = xdbl[row * 96 + 80 + jj];
        size_t off = row * DIN + dbase + jj;
        ushort_t dtb = dtfb[off];
        float uv = uc[off];
        sdtp[idx] = (uint_t)dtb | ((uint_t)f2b(b2f(dtb) * uv) << 16);
        suT[jj * 65 + i] = uv;
    }

    // boundary combine: H_{c-1} for this thread's (g, n)
    float hs = 0.f;
    const size_t base_bx = (size_t)(b * 2048 + dgrp * 16);
    for (int cc = 0; cc < c; ++cc) {
        float qv = bnd_q[(base_bx + cc) * 256 + tid];
        float sv = bnd_s[(base_bx + cc) * 16 + g];
        hs = fmaf(__expf(A_dn * sv), hs, qv);
    }
    __syncthreads();

    // serial chunk scan with in-loop DPP reduction over n (rows of 16)
#pragma unroll 8
    for (int i = 0; i < CHL; ++i) {
        uint_t dp = sdtp[i * 16 + g];
        float dtv = __uint_as_float(dp << 16);
        float dtu = __uint_as_float(dp & 0xffff0000u);
        float2 bc = *(const float2*)(sBCi + i * 32 + n * 2);
        float dA  = __expf(dtv * A_dn);
        hs = fmaf(dA, hs, dtu * bc.x);
        float p = hs * bc.y;
        p = rradd<0x128>(p);   // row_ror:8
        p = rradd<0x124>(p);   // row_ror:4
        p = rradd<0x122>(p);   // row_ror:2
        p = rradd<0x121>(p);   // row_ror:1
        if (n == 0) sy3[i * 17 + g] = p;
    }
    __syncthreads();
    // gated coalesced store (+ u*D term)
#pragma unroll
    for (int k = 0; k < 4; ++k) {
        int idx = tid + k * 256; int row = idx >> 4, col = idx & 15;
        float y = sy3[row * 17 + col] + suT[col * 65 + row] * sD[col];
        float z = b2f(xzb[(size_t)(b * L_ + t0 + row) * (2 * DIN) + DIN + dbase + col]);
        y *= z * sigmoidf_(z);
        ucb[(size_t)(b * L_ + t0 + row) * DIN + dbase + col] = f2b(y);
    }
}

extern "C" void kernel_launch(void* const* d_in, const int* in_sizes, int n_in,
                              void* d_out, int out_size, void* d_ws, size_t ws_size,
                              hipStream_t stream)
{
    (void)in_sizes; (void)n_in; (void)out_size; (void)ws_size;
    const float* x      = (const float*)d_in[0];
    const float* W_in   = (const float*)d_in[1];
    const float* conv_w = (const float*)d_in[2];
    const float* conv_b = (const float*)d_in[3];
    const float* W_x    = (const float*)d_in[4];
    const float* W_dt   = (const float*)d_in[5];
    const float* b_dt   = (const float*)d_in[6];
    const float* A_log  = (const float*)d_in[7];
    const float* Dv     = (const float*)d_in[8];
    const float* W_out  = (const float*)d_in[9];
    float* out = (float*)d_out;

    // workspace layout; pws overlays bnd_q/bnd_s (disjoint lifetimes)
    float* uc      = (float*)d_ws;                       // 4,194,304 f32
    float* xdbl    = uc + 4194304;                       //   196,608 f32
    float* bnd_q   = xdbl + 196608;                      // 1,048,576 f32
    float* bnd_s   = bnd_q + 1048576;                    //    65,536 f32
    float* pws     = bnd_q;                              // 1,572,864 f32 (overlay)
    float* f32_end = bnd_q + 1572864;
    ushort_t* dtfb = (ushort_t*)f32_end;                 // 4,194,304 u16
    ushort_t* xzb  = dtfb + 4194304;                     // 8,388,608
    ushort_t* ucb  = xzb + 8388608;                      // 4,194,304
    ushort_t* xdblb= ucb + 4194304;                      //   196,608
    ushort_t* xb   = xdblb + 196608;                     // 2,097,152 (x/h bf16)
    ushort_t* wib  = xb + 2097152;                       // 8,388,608
    ushort_t* wxb  = wib + 8388608;                      //   393,216
    ushort_t* wdb  = wxb + 393216;                       //   262,144
    ushort_t* wob  = wdb + 262144;                       // 4,194,304

    const int M = B_ * L_;
    // converts
    f2b_k<<<2097152 / 256, 256, 0, stream>>>(x, xb, 2097152);
    f2b_k<<<8388608 / 256, 256, 0, stream>>>(W_in, wib, 8388608);
    f2b_k<<<(393216 + 255) / 256, 256, 0, stream>>>(W_x, wxb, 393216);
    f2b_k<<<(262144 + 255) / 256, 256, 0, stream>>>(W_dt, wdb, 262144);
    f2b_k<<<4194304 / 256, 256, 0, stream>>>(W_out, wob, 4194304);

    for (int layer = 0; layer < 2; ++layer) {
        // xzb = bf16( h @ W_in^T )  [M, 4096]
        mgemm<3><<<dim3(4096 / 128, M / 128), 256, 0, stream>>>(
            xb, wib + (size_t)layer * 4194304, nullptr, xzb, nullptr, nullptr,
            M, 2 * DIN, DM, DM, DM);
        // uc/ucb = silu(conv(u) + b)
        conv8_k<<<(B_ * L_ * DIN / 8) / 256, 256, 0, stream>>>(
            xzb, conv_w + (size_t)layer * DIN * 4, conv_b + (size_t)layer * DIN, uc, ucb);
        // xdbl = uc @ W_x^T  [M, 96]  (split-K x8 + reduce)
        mgemm_sk<<<dim3(1, M / 128, 8), 256, 0, stream>>>(
            ucb, wxb + (size_t)layer * 196608, pws, M, 96, DIN / 8, DIN, DIN);
        wxred_k<<<196608 / 256, 256, 0, stream>>>(pws, xdbl, xdblb);
        // dtfb = bf16(softplus(xdblb[:, :64] @ W_dt^T + b_dt))  [M, 2048]
        mgemm<2><<<dim3(2048 / 128, M / 128), 256, 0, stream>>>(
            xdblb, wdb + (size_t)layer * 131072, nullptr, dtfb,
            b_dt + (size_t)layer * DIN, nullptr, M, DIN, DTR, 96, DTR);
        // chunk-parallel scan
        scan_s1<<<4096, 256, 0, stream>>>(dtfb, uc, xdbl,
            A_log + (size_t)layer * DIN * DS, bnd_q, bnd_s);
        scan_s2<<<4096, 256, 0, stream>>>(dtfb, uc, xdbl, xzb,
            A_log + (size_t)layer * DIN * DS, Dv + (size_t)layer * DIN,
            bnd_q, bnd_s, ucb);
        // out-proj (128x64 tiles): layer0 -> xb (bf16 h); layer1 -> out = acc + x
        if (layer == 0)
            mgemm_n64<3><<<dim3(1024 / 64, M / 128), 256, 0, stream>>>(
                ucb, wob + (size_t)layer * 2097152, nullptr, xb, nullptr,
                M, DM, DIN, DIN, DIN);
        else
            mgemm_n64<4><<<dim3(1024 / 64, M / 128), 256, 0, stream>>>(
                ucb, wob + (size_t)layer * 2097152, out, nullptr, x,
                M, DM, DIN, DIN, DIN);
    }
}

// Round 6
// 479.433 us; speedup vs baseline: 1.2957x; 1.0316x over previous
//
#include <hip/hip_runtime.h>
#include <hip/hip_bf16.h>
#include <math.h>

#define B_ 2
#define L_ 1024
#define DM 1024
#define DIN 2048
#define DS 16
#define DTR 64
#define CHL 32      // chunk length
#define NCH 32      // chunks per sequence

typedef __attribute__((ext_vector_type(8))) short bf16x8;
typedef __attribute__((ext_vector_type(8))) unsigned short u16x8;
typedef __attribute__((ext_vector_type(4))) float f32x4;
typedef unsigned short ushort_t;
typedef unsigned int uint_t;

__device__ __forceinline__ float sigmoidf_(float x) { return 1.f / (1.f + __expf(-x)); }
__device__ __forceinline__ ushort_t f2b(float f) {
    uint_t b = __float_as_uint(f);
    return (ushort_t)((b + 0x7FFFu + ((b >> 16) & 1u)) >> 16);
}
__device__ __forceinline__ float b2f(ushort_t u) {
    return __uint_as_float(((uint_t)u) << 16);
}

// fused f32 -> bf16 (RTN) for x + all weights, one dispatch
__global__ __launch_bounds__(256) void f2b_all_k(
    const float* __restrict__ s0, ushort_t* __restrict__ d0, int n0,   // x
    const float* __restrict__ s1, ushort_t* __restrict__ d1, int n1,   // W_in
    const float* __restrict__ s2, ushort_t* __restrict__ d2, int n2,   // W_x
    const float* __restrict__ s3, ushort_t* __restrict__ d3, int n3,   // W_dt
    const float* __restrict__ s4, ushort_t* __restrict__ d4, int n4)   // W_out
{
    int i = blockIdx.x * 256 + threadIdx.x;
    if (i < n0) d0[i] = f2b(s0[i]);
    i -= n0;
    if (i >= 0 && i < n1) d1[i] = f2b(s1[i]);
    i -= n1;
    if (i >= 0 && i < n2) d2[i] = f2b(s2[i]);
    i -= n2;
    if (i >= 0 && i < n3) d3[i] = f2b(s3[i]);
    i -= n3;
    if (i >= 0 && i < n4) d4[i] = f2b(s4[i]);
}

// XCD-aware bijective swizzle of linear wg id (nwg % 8 == 0)
__device__ __forceinline__ int xcd_swz(int wgid, int nwg) {
    int cpx = nwg >> 3;
    return (wgid & 7) * cpx + (wgid >> 3);
}

// ---------------- MFMA GEMM 128x128: C = A[M,K] * Bt[N,K]^T --------------------
// EPI: 2 = bf16 Cb = softplus(C + bias[n]); 3 = bf16 only
template<int EPI>
__global__ __launch_bounds__(256) void mgemm(const ushort_t* __restrict__ A,
    const ushort_t* __restrict__ Bt, float* __restrict__ Cf, ushort_t* __restrict__ Cb,
    const float* __restrict__ bias, int M, int N, int K, int lda, int ldb)
{
    __shared__ ushort_t sA[128 * 32];
    __shared__ ushort_t sB[128 * 32];
    const int tid = threadIdx.x;
    const int lane = tid & 63, wv = tid >> 6;
    const int wm = wv >> 1, wn = wv & 1;
    const int swz = xcd_swz(blockIdx.y * gridDim.x + blockIdx.x, gridDim.x * gridDim.y);
    const int m0 = (swz / gridDim.x) * 128, n0 = (swz % gridDim.x) * 128;
    const int sr = tid >> 2;
    const int sc = (tid & 3) * 8;
    f32x4 acc[4][4] = {};

    for (int k0 = 0; k0 < K; k0 += 32) {
#pragma unroll
        for (int j = 0; j < 2; ++j) {
            int ra = sr + j * 64;
            int ga = m0 + ra;
            __builtin_amdgcn_global_load_lds(
                (const uint_t*)(A + (size_t)ga * lda + k0 + sc),
                (uint_t*)(sA + ra * 32 + sc), 16, 0, 0);
            int gb = n0 + ra; if (gb >= N) gb = N - 1;
            __builtin_amdgcn_global_load_lds(
                (const uint_t*)(Bt + (size_t)gb * ldb + k0 + sc),
                (uint_t*)(sB + ra * 32 + sc), 16, 0, 0);
        }
        __syncthreads();
        bf16x8 af[4], bfr[4];
#pragma unroll
        for (int i = 0; i < 4; ++i) {
            af[i]  = *(const bf16x8*)(sA + (wm * 64 + i * 16 + (lane & 15)) * 32 + (lane >> 4) * 8);
            bfr[i] = *(const bf16x8*)(sB + (wn * 64 + i * 16 + (lane & 15)) * 32 + (lane >> 4) * 8);
        }
#pragma unroll
        for (int i = 0; i < 4; ++i)
#pragma unroll
            for (int jj = 0; jj < 4; ++jj)
                acc[i][jj] = __builtin_amdgcn_mfma_f32_16x16x32_bf16(af[i], bfr[jj], acc[i][jj], 0, 0, 0);
        __syncthreads();
    }

    const int cr = (lane >> 4) * 4, cc = lane & 15;
#pragma unroll
    for (int i = 0; i < 4; ++i) {
        int mrow = m0 + wm * 64 + i * 16 + cr;
#pragma unroll
        for (int jj = 0; jj < 4; ++jj) {
            int ncol = n0 + wn * 64 + jj * 16 + cc;
            if (ncol < N) {
#pragma unroll
                for (int r = 0; r < 4; ++r) {
                    float v = acc[i][jj][r];
                    size_t off = (size_t)(mrow + r) * N + ncol;
                    if (EPI == 2) {
                        float s = v + bias[ncol];
                        Cb[off] = f2b((s > 20.f) ? s : log1pf(expf(s)));
                    }
                    else { Cb[off] = f2b(v); }
                }
            }
        }
    }
    (void)Cf;
}

// ---------------- MFMA GEMM 128xK split-K (for N=96 W_x proj) ------------------
__global__ __launch_bounds__(256) void mgemm_sk(const ushort_t* __restrict__ A,
    const ushort_t* __restrict__ Bt, float* __restrict__ P,
    int M, int N, int Kslice, int lda, int ldb)
{
    __shared__ ushort_t sA[128 * 32];
    __shared__ ushort_t sB[128 * 32];
    const int tid = threadIdx.x;
    const int lane = tid & 63, wv = tid >> 6;
    const int wm = wv >> 1, wn = wv & 1;
    const int m0 = blockIdx.y * 128;
    const int kbase = blockIdx.z * Kslice;
    const int sr = tid >> 2;
    const int sc = (tid & 3) * 8;
    f32x4 acc[4][4] = {};

    for (int k0 = kbase; k0 < kbase + Kslice; k0 += 32) {
#pragma unroll
        for (int j = 0; j < 2; ++j) {
            int ra = sr + j * 64;
            __builtin_amdgcn_global_load_lds(
                (const uint_t*)(A + (size_t)(m0 + ra) * lda + k0 + sc),
                (uint_t*)(sA + ra * 32 + sc), 16, 0, 0);
            int gb = ra; if (gb >= N) gb = N - 1;
            __builtin_amdgcn_global_load_lds(
                (const uint_t*)(Bt + (size_t)gb * ldb + k0 + sc),
                (uint_t*)(sB + ra * 32 + sc), 16, 0, 0);
        }
        __syncthreads();
        bf16x8 af[4], bfr[4];
#pragma unroll
        for (int i = 0; i < 4; ++i) {
            af[i]  = *(const bf16x8*)(sA + (wm * 64 + i * 16 + (lane & 15)) * 32 + (lane >> 4) * 8);
            bfr[i] = *(const bf16x8*)(sB + (wn * 64 + i * 16 + (lane & 15)) * 32 + (lane >> 4) * 8);
        }
#pragma unroll
        for (int i = 0; i < 4; ++i)
#pragma unroll
            for (int jj = 0; jj < 4; ++jj)
                acc[i][jj] = __builtin_amdgcn_mfma_f32_16x16x32_bf16(af[i], bfr[jj], acc[i][jj], 0, 0, 0);
        __syncthreads();
    }

    const int cr = (lane >> 4) * 4, cc = lane & 15;
    float* Pz = P + (size_t)blockIdx.z * M * 96;
#pragma unroll
    for (int i = 0; i < 4; ++i) {
        int mrow = m0 + wm * 64 + i * 16 + cr;
#pragma unroll
        for (int jj = 0; jj < 4; ++jj) {
            int ncol = wn * 64 + jj * 16 + cc;
            if (ncol < 96) {
#pragma unroll
                for (int r = 0; r < 4; ++r)
                    Pz[(size_t)(mrow + r) * 96 + ncol] = acc[i][jj][r];
            }
        }
    }
}

// reduce split-K partials -> xdbl f32 + xdblb bf16
__global__ __launch_bounds__(256) void wxred_k(const float* __restrict__ P,
    float* __restrict__ xdbl, ushort_t* __restrict__ xdblb)
{
    int idx = blockIdx.x * 256 + threadIdx.x;
    float s = 0.f;
#pragma unroll
    for (int z = 0; z < 8; ++z) s += P[(size_t)z * 196608 + idx];
    xdbl[idx] = s;
    xdblb[idx] = f2b(s);
}

// ---------------- MFMA GEMM 128x64 (for N=1024 out-proj) -----------------------
// EPI: 3 = bf16 only; 4 = f32 C = acc + res
template<int EPI>
__global__ __launch_bounds__(256) void mgemm_n64(const ushort_t* __restrict__ A,
    const ushort_t* __restrict__ Bt, float* __restrict__ Cf, ushort_t* __restrict__ Cb,
    const float* __restrict__ res, int M, int N, int K, int lda, int ldb)
{
    __shared__ ushort_t sA[128 * 32];
    __shared__ ushort_t sB[64 * 32];
    const int tid = threadIdx.x;
    const int lane = tid & 63, wv = tid >> 6;
    const int swz = xcd_swz(blockIdx.y * gridDim.x + blockIdx.x, gridDim.x * gridDim.y);
    const int m0 = (swz / gridDim.x) * 128, n0 = (swz % gridDim.x) * 64;
    const int sr = tid >> 2;
    const int sc = (tid & 3) * 8;
    f32x4 acc[2][4] = {};

    for (int k0 = 0; k0 < K; k0 += 32) {
#pragma unroll
        for (int j = 0; j < 2; ++j) {
            int ra = sr + j * 64;
            __builtin_amdgcn_global_load_lds(
                (const uint_t*)(A + (size_t)(m0 + ra) * lda + k0 + sc),
                (uint_t*)(sA + ra * 32 + sc), 16, 0, 0);
        }
        __builtin_amdgcn_global_load_lds(
            (const uint_t*)(Bt + (size_t)(n0 + sr) * ldb + k0 + sc),
            (uint_t*)(sB + sr * 32 + sc), 16, 0, 0);
        __syncthreads();
        bf16x8 af[2], bfr[4];
#pragma unroll
        for (int i = 0; i < 2; ++i)
            af[i]  = *(const bf16x8*)(sA + (wv * 32 + i * 16 + (lane & 15)) * 32 + (lane >> 4) * 8);
#pragma unroll
        for (int jj = 0; jj < 4; ++jj)
            bfr[jj] = *(const bf16x8*)(sB + (jj * 16 + (lane & 15)) * 32 + (lane >> 4) * 8);
#pragma unroll
        for (int i = 0; i < 2; ++i)
#pragma unroll
            for (int jj = 0; jj < 4; ++jj)
                acc[i][jj] = __builtin_amdgcn_mfma_f32_16x16x32_bf16(af[i], bfr[jj], acc[i][jj], 0, 0, 0);
        __syncthreads();
    }

    const int cr = (lane >> 4) * 4, cc = lane & 15;
#pragma unroll
    for (int i = 0; i < 2; ++i) {
        int mrow = m0 + wv * 32 + i * 16 + cr;
#pragma unroll
        for (int jj = 0; jj < 4; ++jj) {
            int ncol = n0 + jj * 16 + cc;
#pragma unroll
            for (int r = 0; r < 4; ++r) {
                float v = acc[i][jj][r];
                size_t off = (size_t)(mrow + r) * N + ncol;
                if (EPI == 3) Cb[off] = f2b(v);
                else Cf[off] = v + res[off];
            }
        }
    }
}

// conv + silu, 8 channels per thread (bf16 out only)
__global__ __launch_bounds__(256) void conv8_k(const ushort_t* __restrict__ xzb,
    const float* __restrict__ cw, const float* __restrict__ cb,
    ushort_t* __restrict__ ucb)
{
    int idx8 = blockIdx.x * 256 + threadIdx.x;      // over B*L*DIN/8
    int d8 = (idx8 & 255) * 8;
    int t = (idx8 >> 8) & (L_ - 1);
    int b = idx8 >> 18;
    const ushort_t* base = xzb + (size_t)b * L_ * (2 * DIN) + d8;
    float acc[8];
    const float4* cb4 = (const float4*)(cb + d8);
    float4 cbl = cb4[0], cbh = cb4[1];
#pragma unroll
    for (int e = 0; e < 4; ++e) { acc[e] = ((const float*)&cbl)[e]; acc[4 + e] = ((const float*)&cbh)[e]; }
    float4 cwv[8];
#pragma unroll
    for (int e = 0; e < 8; ++e) cwv[e] = ((const float4*)cw)[d8 + e];
#pragma unroll
    for (int j = 0; j < 4; ++j) {
        int tt = t - 3 + j;
        if (tt >= 0) {
            u16x8 row = *(const u16x8*)(base + (size_t)tt * (2 * DIN));
#pragma unroll
            for (int e = 0; e < 8; ++e)
                acc[e] = fmaf(((const float*)&cwv[e])[j], b2f(row[e]), acc[e]);
        }
    }
    u16x8 ob;
#pragma unroll
    for (int e = 0; e < 8; ++e) {
        float v = acc[e] * sigmoidf_(acc[e]);
        ob[e] = f2b(v);
    }
    *(u16x8*)(ucb + (size_t)idx8 * 8) = ob;
}

// ---------------- chunk-parallel scan, 16 states per THREAD -------------------
// grid: b(2) x chunks(32) x dgroups(8 of 256); thread = one channel d.
// S1: local scan from zero -> bnd_q[(b,c,d),n], bnd_s[(b,c,d)]
__global__ __launch_bounds__(256, 2) void scan_s1(const ushort_t* __restrict__ dtfb,
    const ushort_t* __restrict__ ucb, const float* __restrict__ xdbl,
    const float* __restrict__ A_log,
    float* __restrict__ bnd_q, float* __restrict__ bnd_s)
{
    __shared__ uint_t sdt[CHL * 256];    // {dt.bf16 lo, u.bf16 hi}
    __shared__ float sB[CHL * 16];
    const int tid = threadIdx.x;
    const int bx = blockIdx.x;
    const int dg = bx & 7, c = (bx >> 3) & 31, b = bx >> 8;
    const int d = dg * 256 + tid;
    const int row0 = b * L_ + c * CHL;

    float A_dn[16];
#pragma unroll
    for (int n = 0; n < 16; ++n) A_dn[n] = -__expf(A_log[(size_t)d * DS + n]);

    // stage dt/u (coalesced) and B
    for (int k = 0; k < CHL; ++k) {
        size_t off = (size_t)(row0 + k) * DIN + d;
        sdt[k * 256 + tid] = (uint_t)dtfb[off] | ((uint_t)ucb[off] << 16);
    }
#pragma unroll
    for (int j = 0; j < 2; ++j) {
        int idx = tid + j * 256;                 // CHL*16 = 512
        int t = idx >> 4, n = idx & 15;
        sB[idx] = xdbl[(size_t)(row0 + t) * 96 + 64 + n];
    }
    __syncthreads();

    float q[16];
#pragma unroll
    for (int n = 0; n < 16; ++n) q[n] = 0.f;
    float s = 0.f;
    for (int k = 0; k < CHL; ++k) {
        uint_t pk = sdt[k * 256 + tid];
        float dtv = __uint_as_float(pk << 16);
        float uv  = __uint_as_float(pk & 0xffff0000u);
        float dtu = dtv * uv;
        s += dtv;
        f32x4 Bq[4];
#pragma unroll
        for (int j = 0; j < 4; ++j) Bq[j] = *(const f32x4*)(sB + k * 16 + j * 4);
#pragma unroll
        for (int n = 0; n < 16; ++n)
            q[n] = fmaf(__expf(dtv * A_dn[n]), q[n], dtu * Bq[n >> 2][n & 3]);
    }
    float* qp = bnd_q + ((size_t)(b * NCH + c) * DIN + d) * 16;
#pragma unroll
    for (int j = 0; j < 4; ++j)
        *(f32x4*)(qp + j * 4) = (f32x4){q[j * 4], q[j * 4 + 1], q[j * 4 + 2], q[j * 4 + 3]};
    bnd_s[(size_t)(b * NCH + c) * DIN + d] = s;
}

// B2: sequential combine over chunks -> Hini[(b,c,d),n] (state BEFORE chunk c)
__global__ __launch_bounds__(256) void scan_b2(const float* __restrict__ bnd_q,
    const float* __restrict__ bnd_s, const float* __restrict__ A_log,
    float* __restrict__ Hini)
{
    int glob = blockIdx.x * 256 + threadIdx.x;    // b * DIN * 16
    int n = glob & 15, d = (glob >> 4) & (DIN - 1), b = glob >> 15;
    float A_dn = -__expf(A_log[(size_t)d * DS + n]);
    float H = 0.f;
    for (int c = 0; c < NCH; ++c) {
        size_t idx = (size_t)(b * NCH + c) * DIN + d;
        Hini[idx * 16 + n] = H;
        H = fmaf(__expf(A_dn * bnd_s[idx]), H, bnd_q[idx * 16 + n]);
    }
}

// S2: rescan chunk from Hini, y = C.h + u*D, gate silu(z), write bf16 ucb (in place)
__global__ __launch_bounds__(256, 2) void scan_s2(const ushort_t* __restrict__ dtfb,
    const ushort_t* __restrict__ ucb_in, const float* __restrict__ xdbl,
    const ushort_t* __restrict__ xzb, const float* __restrict__ A_log,
    const float* __restrict__ Dvec, const float* __restrict__ Hini,
    ushort_t* __restrict__ ucb_out)
{
    __shared__ uint_t sdt[CHL * 256];    // {dt.bf16 lo, u.bf16 hi}
    __shared__ float sBC[CHL * 32];      // [t][n*2 {B,C}]
    __shared__ float sy[CHL * 256];      // y f32
    const int tid = threadIdx.x;
    const int bx = blockIdx.x;
    const int dg = bx & 7, c = (bx >> 3) & 31, b = bx >> 8;
    const int d = dg * 256 + tid;
    const int row0 = b * L_ + c * CHL;
    const float Dd = Dvec[d];

    float A_dn[16];
#pragma unroll
    for (int n = 0; n < 16; ++n) A_dn[n] = -__expf(A_log[(size_t)d * DS + n]);

    for (int k = 0; k < CHL; ++k) {
        size_t off = (size_t)(row0 + k) * DIN + d;
        sdt[k * 256 + tid] = (uint_t)dtfb[off] | ((uint_t)ucb_in[off] << 16);
    }
#pragma unroll
    for (int j = 0; j < 4; ++j) {
        int idx = tid + j * 256;                 // CHL*32 = 1024
        int t = idx >> 5, jj = idx & 31;         // jj = n*2 + {0:B,1:C}
        sBC[idx] = xdbl[(size_t)(row0 + t) * 96 + 64 + (jj & 1) * 16 + (jj >> 1)];
    }

    // initial state for this chunk
    float h[16];
    const float* hp = Hini + ((size_t)(b * NCH + c) * DIN + d) * 16;
#pragma unroll
    for (int j = 0; j < 4; ++j) {
        f32x4 hv = *(const f32x4*)(hp + j * 4);
#pragma unroll
        for (int e = 0; e < 4; ++e) h[j * 4 + e] = hv[e];
    }
    __syncthreads();

    for (int k = 0; k < CHL; ++k) {
        uint_t pk = sdt[k * 256 + tid];
        float dtv = __uint_as_float(pk << 16);
        float uv  = __uint_as_float(pk & 0xffff0000u);
        float dtu = dtv * uv;
        float y = uv * Dd;
        f32x4 bcq[8];
#pragma unroll
        for (int j = 0; j < 8; ++j) bcq[j] = *(const f32x4*)(sBC + k * 32 + j * 4);
#pragma unroll
        for (int n = 0; n < 16; ++n) {
            float Bv = bcq[n >> 1][(n & 1) * 2];
            float Cv = bcq[n >> 1][(n & 1) * 2 + 1];
            h[n] = fmaf(__expf(dtv * A_dn[n]), h[n], dtu * Bv);
            y = fmaf(h[n], Cv, y);
        }
        sy[k * 256 + tid] = y;
    }
    __syncthreads();
    // gate + store
    for (int k = 0; k < CHL; ++k) {
        float y = sy[k * 256 + tid];
        float z = b2f(xzb[(size_t)(row0 + k) * (2 * DIN) + DIN + d]);
        y *= z * sigmoidf_(z);
        ucb_out[(size_t)(row0 + k) * DIN + d] = f2b(y);
    }
}

extern "C" void kernel_launch(void* const* d_in, const int* in_sizes, int n_in,
                              void* d_out, int out_size, void* d_ws, size_t ws_size,
                              hipStream_t stream)
{
    (void)in_sizes; (void)n_in; (void)out_size; (void)ws_size;
    const float* x      = (const float*)d_in[0];
    const float* W_in   = (const float*)d_in[1];
    const float* conv_w = (const float*)d_in[2];
    const float* conv_b = (const float*)d_in[3];
    const float* W_x    = (const float*)d_in[4];
    const float* W_dt   = (const float*)d_in[5];
    const float* b_dt   = (const float*)d_in[6];
    const float* A_log  = (const float*)d_in[7];
    const float* Dv     = (const float*)d_in[8];
    const float* W_out  = (const float*)d_in[9];
    float* out = (float*)d_out;

    // workspace layout
    float* xdbl    = (float*)d_ws;                       //   196,608 f32
    float* pws     = xdbl + 196608;                      // 1,572,864 f32
    float* bnd_q   = pws + 1572864;                      // 2,097,152 f32
    float* bnd_s   = bnd_q + 2097152;                    //   131,072 f32
    float* Hini    = bnd_s + 131072;                     // 2,097,152 f32
    ushort_t* dtfb = (ushort_t*)(Hini + 2097152);        // 4,194,304 u16
    ushort_t* xzb  = dtfb + 4194304;                     // 8,388,608
    ushort_t* ucb  = xzb + 8388608;                      // 4,194,304
    ushort_t* xdblb= ucb + 4194304;                      //   196,608
    ushort_t* xb   = xdblb + 196608;                     // 2,097,152 (x/h bf16)
    ushort_t* wib  = xb + 2097152;                       // 8,388,608
    ushort_t* wxb  = wib + 8388608;                      //   393,216
    ushort_t* wdb  = wxb + 393216;                       //   262,144
    ushort_t* wob  = wdb + 262144;                       // 4,194,304

    const int M = B_ * L_;
    // one fused convert pass (x + 4 weight tensors)
    const int NT = 2097152 + 8388608 + 393216 + 262144 + 4194304;
    f2b_all_k<<<(NT + 255) / 256, 256, 0, stream>>>(
        x, xb, 2097152, W_in, wib, 8388608, W_x, wxb, 393216,
        W_dt, wdb, 262144, W_out, wob, 4194304);

    for (int layer = 0; layer < 2; ++layer) {
        // xzb = bf16( h @ W_in^T )  [M, 4096]
        mgemm<3><<<dim3(4096 / 128, M / 128), 256, 0, stream>>>(
            xb, wib + (size_t)layer * 4194304, nullptr, xzb, nullptr,
            M, 2 * DIN, DM, DM, DM);
        // ucb = bf16(silu(conv(u) + b))
        conv8_k<<<(B_ * L_ * DIN / 8) / 256, 256, 0, stream>>>(
            xzb, conv_w + (size_t)layer * DIN * 4, conv_b + (size_t)layer * DIN, ucb);
        // xdbl = uc @ W_x^T  [M, 96]  (split-K x8 + reduce)
        mgemm_sk<<<dim3(1, M / 128, 8), 256, 0, stream>>>(
            ucb, wxb + (size_t)layer * 196608, pws, M, 96, DIN / 8, DIN, DIN);
        wxred_k<<<196608 / 256, 256, 0, stream>>>(pws, xdbl, xdblb);
        // dtfb = bf16(softplus(xdblb[:, :64] @ W_dt^T + b_dt))  [M, 2048]
        mgemm<2><<<dim3(2048 / 128, M / 128), 256, 0, stream>>>(
            xdblb, wdb + (size_t)layer * 131072, nullptr, dtfb,
            b_dt + (size_t)layer * DIN, M, DIN, DTR, 96, DTR);
        // chunk-parallel scan (states-in-registers mapping)
        const float* Al = A_log + (size_t)layer * DIN * DS;
        scan_s1<<<B_ * NCH * 8, 256, 0, stream>>>(dtfb, ucb, xdbl, Al, bnd_q, bnd_s);
        scan_b2<<<(B_ * DIN * 16) / 256, 256, 0, stream>>>(bnd_q, bnd_s, Al, Hini);
        scan_s2<<<B_ * NCH * 8, 256, 0, stream>>>(dtfb, ucb, xdbl, xzb, Al,
            Dv + (size_t)layer * DIN, Hini, ucb);
        // out-proj (128x64 tiles): layer0 -> xb (bf16 h); layer1 -> out = acc + x
        if (layer == 0)
            mgemm_n64<3><<<dim3(1024 / 64, M / 128), 256, 0, stream>>>(
                ucb, wob + (size_t)layer * 2097152, nullptr, xb, nullptr,
                M, DM, DIN, DIN, DIN);
        else
            mgemm_n64<4><<<dim3(1024 / 64, M / 128), 256, 0, stream>>>(
                ucb, wob + (size_t)layer * 2097152, out, nullptr, x,
                M, DM, DIN, DIN, DIN);
    }
}

// Round 7
// 449.314 us; speedup vs baseline: 1.3826x; 1.0670x over previous
//
#include <hip/hip_runtime.h>
#include <hip/hip_bf16.h>
#include <math.h>

#define B_ 2
#define L_ 1024
#define DM 1024
#define DIN 2048
#define DS 16
#define DTR 64
#define CHL 32      // chunk length
#define NCH 32      // chunks per sequence

typedef __attribute__((ext_vector_type(8))) short bf16x8;
typedef __attribute__((ext_vector_type(8))) unsigned short u16x8;
typedef __attribute__((ext_vector_type(4))) unsigned short u16x4;
typedef __attribute__((ext_vector_type(4))) float f32x4;
typedef unsigned short ushort_t;
typedef unsigned int uint_t;

__device__ __forceinline__ float sigmoidf_(float x) { return 1.f / (1.f + __expf(-x)); }
__device__ __forceinline__ ushort_t f2b(float f) {
    uint_t b = __float_as_uint(f);
    return (ushort_t)((b + 0x7FFFu + ((b >> 16) & 1u)) >> 16);
}
__device__ __forceinline__ float b2f(ushort_t u) {
    return __uint_as_float(((uint_t)u) << 16);
}

// fused f32 -> bf16 (RTN), 4 elems/thread
__global__ __launch_bounds__(256) void f2b_all_k(
    const float* __restrict__ s0, ushort_t* __restrict__ d0, int n0,
    const float* __restrict__ s1, ushort_t* __restrict__ d1, int n1,
    const float* __restrict__ s2, ushort_t* __restrict__ d2, int n2,
    const float* __restrict__ s3, ushort_t* __restrict__ d3, int n3,
    const float* __restrict__ s4, ushort_t* __restrict__ d4, int n4)
{
    int i = (blockIdx.x * 256 + threadIdx.x) * 4;
    const float* s; ushort_t* d;
    if (i < n0) { s = s0; d = d0; }
    else { i -= n0;
    if (i < n1) { s = s1; d = d1; }
    else { i -= n1;
    if (i < n2) { s = s2; d = d2; }
    else { i -= n2;
    if (i < n3) { s = s3; d = d3; }
    else { i -= n3;
    if (i < n4) { s = s4; d = d4; }
    else return; }}}}
    float4 v = *(const float4*)(s + i);
    u16x4 o;
    o[0] = f2b(v.x); o[1] = f2b(v.y); o[2] = f2b(v.z); o[3] = f2b(v.w);
    *(u16x4*)(d + i) = o;
}

// XCD-aware bijective swizzle of linear wg id (nwg % 8 == 0)
__device__ __forceinline__ int xcd_swz(int wgid, int nwg) {
    int cpx = nwg >> 3;
    return (wgid & 7) * cpx + (wgid >> 3);
}

// ---------------- MFMA GEMM 128x128, double-buffered prefetch ------------------
// EPI: 2 = bf16 Cb = softplus(C + bias[n]); 3 = bf16 only
template<int EPI>
__global__ __launch_bounds__(256) void mgemm(const ushort_t* __restrict__ A,
    const ushort_t* __restrict__ Bt, float* __restrict__ Cf, ushort_t* __restrict__ Cb,
    const float* __restrict__ bias, int M, int N, int K, int lda, int ldb)
{
    __shared__ ushort_t sA[2][128 * 32];
    __shared__ ushort_t sB[2][128 * 32];
    const int tid = threadIdx.x;
    const int lane = tid & 63, wv = tid >> 6;
    const int wm = wv >> 1, wn = wv & 1;
    const int swz = xcd_swz(blockIdx.y * gridDim.x + blockIdx.x, gridDim.x * gridDim.y);
    const int m0 = (swz / gridDim.x) * 128, n0 = (swz % gridDim.x) * 128;
    const int sr = tid >> 2;
    const int sc = (tid & 3) * 8;
    f32x4 acc[4][4] = {};

#pragma unroll
    for (int j = 0; j < 2; ++j) {                     // prologue stage buf0
        int ra = sr + j * 64;
        __builtin_amdgcn_global_load_lds(
            (const uint_t*)(A + (size_t)(m0 + ra) * lda + sc),
            (uint_t*)(sA[0] + ra * 32 + sc), 16, 0, 0);
        int gb = n0 + ra; if (gb >= N) gb = N - 1;
        __builtin_amdgcn_global_load_lds(
            (const uint_t*)(Bt + (size_t)gb * ldb + sc),
            (uint_t*)(sB[0] + ra * 32 + sc), 16, 0, 0);
    }
    __syncthreads();
    int cur = 0;
    for (int k0 = 0; k0 < K; k0 += 32) {
        if (k0 + 32 < K) {                            // prefetch next into other buf
            int nxt = cur ^ 1;
#pragma unroll
            for (int j = 0; j < 2; ++j) {
                int ra = sr + j * 64;
                __builtin_amdgcn_global_load_lds(
                    (const uint_t*)(A + (size_t)(m0 + ra) * lda + k0 + 32 + sc),
                    (uint_t*)(sA[nxt] + ra * 32 + sc), 16, 0, 0);
                int gb = n0 + ra; if (gb >= N) gb = N - 1;
                __builtin_amdgcn_global_load_lds(
                    (const uint_t*)(Bt + (size_t)gb * ldb + k0 + 32 + sc),
                    (uint_t*)(sB[nxt] + ra * 32 + sc), 16, 0, 0);
            }
        }
        bf16x8 af[4], bfr[4];
#pragma unroll
        for (int i = 0; i < 4; ++i) {
            af[i]  = *(const bf16x8*)(sA[cur] + (wm * 64 + i * 16 + (lane & 15)) * 32 + (lane >> 4) * 8);
            bfr[i] = *(const bf16x8*)(sB[cur] + (wn * 64 + i * 16 + (lane & 15)) * 32 + (lane >> 4) * 8);
        }
#pragma unroll
        for (int i = 0; i < 4; ++i)
#pragma unroll
            for (int jj = 0; jj < 4; ++jj)
                acc[i][jj] = __builtin_amdgcn_mfma_f32_16x16x32_bf16(af[i], bfr[jj], acc[i][jj], 0, 0, 0);
        __syncthreads();                              // drains prefetch vmcnt too
        cur ^= 1;
    }

    const int cr = (lane >> 4) * 4, cc = lane & 15;
#pragma unroll
    for (int i = 0; i < 4; ++i) {
        int mrow = m0 + wm * 64 + i * 16 + cr;
#pragma unroll
        for (int jj = 0; jj < 4; ++jj) {
            int ncol = n0 + wn * 64 + jj * 16 + cc;
            if (ncol < N) {
#pragma unroll
                for (int r = 0; r < 4; ++r) {
                    float v = acc[i][jj][r];
                    size_t off = (size_t)(mrow + r) * N + ncol;
                    if (EPI == 2) {
                        float s = v + bias[ncol];
                        Cb[off] = f2b((s > 20.f) ? s : log1pf(expf(s)));
                    }
                    else { Cb[off] = f2b(v); }
                }
            }
        }
    }
    (void)Cf;
}

// ---------------- MFMA GEMM 128xK split-K (N=96 W_x proj), dbuf ----------------
__global__ __launch_bounds__(256) void mgemm_sk(const ushort_t* __restrict__ A,
    const ushort_t* __restrict__ Bt, float* __restrict__ P,
    int M, int N, int Kslice, int lda, int ldb)
{
    __shared__ ushort_t sA[2][128 * 32];
    __shared__ ushort_t sB[2][128 * 32];
    const int tid = threadIdx.x;
    const int lane = tid & 63, wv = tid >> 6;
    const int wm = wv >> 1, wn = wv & 1;
    const int m0 = blockIdx.y * 128;
    const int kbase = blockIdx.z * Kslice;
    const int sr = tid >> 2;
    const int sc = (tid & 3) * 8;
    f32x4 acc[4][4] = {};

#pragma unroll
    for (int j = 0; j < 2; ++j) {
        int ra = sr + j * 64;
        __builtin_amdgcn_global_load_lds(
            (const uint_t*)(A + (size_t)(m0 + ra) * lda + kbase + sc),
            (uint_t*)(sA[0] + ra * 32 + sc), 16, 0, 0);
        int gb = ra; if (gb >= N) gb = N - 1;
        __builtin_amdgcn_global_load_lds(
            (const uint_t*)(Bt + (size_t)gb * ldb + kbase + sc),
            (uint_t*)(sB[0] + ra * 32 + sc), 16, 0, 0);
    }
    __syncthreads();
    int cur = 0;
    for (int k0 = kbase; k0 < kbase + Kslice; k0 += 32) {
        if (k0 + 32 < kbase + Kslice) {
            int nxt = cur ^ 1;
#pragma unroll
            for (int j = 0; j < 2; ++j) {
                int ra = sr + j * 64;
                __builtin_amdgcn_global_load_lds(
                    (const uint_t*)(A + (size_t)(m0 + ra) * lda + k0 + 32 + sc),
                    (uint_t*)(sA[nxt] + ra * 32 + sc), 16, 0, 0);
                int gb = ra; if (gb >= N) gb = N - 1;
                __builtin_amdgcn_global_load_lds(
                    (const uint_t*)(Bt + (size_t)gb * ldb + k0 + 32 + sc),
                    (uint_t*)(sB[nxt] + ra * 32 + sc), 16, 0, 0);
            }
        }
        bf16x8 af[4], bfr[4];
#pragma unroll
        for (int i = 0; i < 4; ++i) {
            af[i]  = *(const bf16x8*)(sA[cur] + (wm * 64 + i * 16 + (lane & 15)) * 32 + (lane >> 4) * 8);
            bfr[i] = *(const bf16x8*)(sB[cur] + (wn * 64 + i * 16 + (lane & 15)) * 32 + (lane >> 4) * 8);
        }
#pragma unroll
        for (int i = 0; i < 4; ++i)
#pragma unroll
            for (int jj = 0; jj < 4; ++jj)
                acc[i][jj] = __builtin_amdgcn_mfma_f32_16x16x32_bf16(af[i], bfr[jj], acc[i][jj], 0, 0, 0);
        __syncthreads();
        cur ^= 1;
    }

    const int cr = (lane >> 4) * 4, cc = lane & 15;
    float* Pz = P + (size_t)blockIdx.z * M * 96;
#pragma unroll
    for (int i = 0; i < 4; ++i) {
        int mrow = m0 + wm * 64 + i * 16 + cr;
#pragma unroll
        for (int jj = 0; jj < 4; ++jj) {
            int ncol = wn * 64 + jj * 16 + cc;
            if (ncol < 96) {
#pragma unroll
                for (int r = 0; r < 4; ++r)
                    Pz[(size_t)(mrow + r) * 96 + ncol] = acc[i][jj][r];
            }
        }
    }
}

// reduce split-K partials -> xdbl f32 + xdblb bf16
__global__ __launch_bounds__(256) void wxred_k(const float* __restrict__ P,
    float* __restrict__ xdbl, ushort_t* __restrict__ xdblb)
{
    int idx = blockIdx.x * 256 + threadIdx.x;
    float s = 0.f;
#pragma unroll
    for (int z = 0; z < 8; ++z) s += P[(size_t)z * 196608 + idx];
    xdbl[idx] = s;
    xdblb[idx] = f2b(s);
}

// ---------------- MFMA GEMM 128x64 (N=1024 out-proj), dbuf ---------------------
// EPI: 3 = bf16 only; 4 = f32 C = acc + res
template<int EPI>
__global__ __launch_bounds__(256) void mgemm_n64(const ushort_t* __restrict__ A,
    const ushort_t* __restrict__ Bt, float* __restrict__ Cf, ushort_t* __restrict__ Cb,
    const float* __restrict__ res, int M, int N, int K, int lda, int ldb)
{
    __shared__ ushort_t sA[2][128 * 32];
    __shared__ ushort_t sB[2][64 * 32];
    const int tid = threadIdx.x;
    const int lane = tid & 63, wv = tid >> 6;
    const int swz = xcd_swz(blockIdx.y * gridDim.x + blockIdx.x, gridDim.x * gridDim.y);
    const int m0 = (swz / gridDim.x) * 128, n0 = (swz % gridDim.x) * 64;
    const int sr = tid >> 2;
    const int sc = (tid & 3) * 8;
    f32x4 acc[2][4] = {};

#pragma unroll
    for (int j = 0; j < 2; ++j) {
        int ra = sr + j * 64;
        __builtin_amdgcn_global_load_lds(
            (const uint_t*)(A + (size_t)(m0 + ra) * lda + sc),
            (uint_t*)(sA[0] + ra * 32 + sc), 16, 0, 0);
    }
    __builtin_amdgcn_global_load_lds(
        (const uint_t*)(Bt + (size_t)(n0 + sr) * ldb + sc),
        (uint_t*)(sB[0] + sr * 32 + sc), 16, 0, 0);
    __syncthreads();
    int cur = 0;
    for (int k0 = 0; k0 < K; k0 += 32) {
        if (k0 + 32 < K) {
            int nxt = cur ^ 1;
#pragma unroll
            for (int j = 0; j < 2; ++j) {
                int ra = sr + j * 64;
                __builtin_amdgcn_global_load_lds(
                    (const uint_t*)(A + (size_t)(m0 + ra) * lda + k0 + 32 + sc),
                    (uint_t*)(sA[nxt] + ra * 32 + sc), 16, 0, 0);
            }
            __builtin_amdgcn_global_load_lds(
                (const uint_t*)(Bt + (size_t)(n0 + sr) * ldb + k0 + 32 + sc),
                (uint_t*)(sB[nxt] + sr * 32 + sc), 16, 0, 0);
        }
        bf16x8 af[2], bfr[4];
#pragma unroll
        for (int i = 0; i < 2; ++i)
            af[i]  = *(const bf16x8*)(sA[cur] + (wv * 32 + i * 16 + (lane & 15)) * 32 + (lane >> 4) * 8);
#pragma unroll
        for (int jj = 0; jj < 4; ++jj)
            bfr[jj] = *(const bf16x8*)(sB[cur] + (jj * 16 + (lane & 15)) * 32 + (lane >> 4) * 8);
#pragma unroll
        for (int i = 0; i < 2; ++i)
#pragma unroll
            for (int jj = 0; jj < 4; ++jj)
                acc[i][jj] = __builtin_amdgcn_mfma_f32_16x16x32_bf16(af[i], bfr[jj], acc[i][jj], 0, 0, 0);
        __syncthreads();
        cur ^= 1;
    }

    const int cr = (lane >> 4) * 4, cc = lane & 15;
#pragma unroll
    for (int i = 0; i < 2; ++i) {
        int mrow = m0 + wv * 32 + i * 16 + cr;
#pragma unroll
        for (int jj = 0; jj < 4; ++jj) {
            int ncol = n0 + jj * 16 + cc;
#pragma unroll
            for (int r = 0; r < 4; ++r) {
                float v = acc[i][jj][r];
                size_t off = (size_t)(mrow + r) * N + ncol;
                if (EPI == 3) Cb[off] = f2b(v);
                else Cf[off] = v + res[off];
            }
        }
    }
}

// conv + silu, 8 channels per thread
__global__ __launch_bounds__(256) void conv8_k(const ushort_t* __restrict__ xzb,
    const float* __restrict__ cw, const float* __restrict__ cb,
    ushort_t* __restrict__ ucb)
{
    int idx8 = blockIdx.x * 256 + threadIdx.x;
    int d8 = (idx8 & 255) * 8;
    int t = (idx8 >> 8) & (L_ - 1);
    int b = idx8 >> 18;
    const ushort_t* base = xzb + (size_t)b * L_ * (2 * DIN) + d8;
    float acc[8];
    const float4* cb4 = (const float4*)(cb + d8);
    float4 cbl = cb4[0], cbh = cb4[1];
#pragma unroll
    for (int e = 0; e < 4; ++e) { acc[e] = ((const float*)&cbl)[e]; acc[4 + e] = ((const float*)&cbh)[e]; }
    float4 cwv[8];
#pragma unroll
    for (int e = 0; e < 8; ++e) cwv[e] = ((const float4*)cw)[d8 + e];
#pragma unroll
    for (int j = 0; j < 4; ++j) {
        int tt = t - 3 + j;
        if (tt >= 0) {
            u16x8 row = *(const u16x8*)(base + (size_t)tt * (2 * DIN));
#pragma unroll
            for (int e = 0; e < 8; ++e)
                acc[e] = fmaf(((const float*)&cwv[e])[j], b2f(row[e]), acc[e]);
        }
    }
    u16x8 ob;
#pragma unroll
    for (int e = 0; e < 8; ++e) {
        float v = acc[e] * sigmoidf_(acc[e]);
        ob[e] = f2b(v);
    }
    *(u16x8*)(ucb + (size_t)idx8 * 8) = ob;
}

// ---------------- chunk-parallel scan, 16 states per THREAD -------------------
// S1: local scan from zero -> bnd_q[(b,c,d),n], bnd_s[(b,c,d)]
__global__ __launch_bounds__(256, 2) void scan_s1(const ushort_t* __restrict__ dtfb,
    const ushort_t* __restrict__ ucb, const float* __restrict__ xdbl,
    const float* __restrict__ A_log,
    float* __restrict__ bnd_q, float* __restrict__ bnd_s)
{
    __shared__ uint_t sdt[CHL * 256];
    __shared__ float sB[CHL * 16];
    const int tid = threadIdx.x;
    const int bx = blockIdx.x;
    const int dg = bx & 7, c = (bx >> 3) & 31, b = bx >> 8;
    const int d = dg * 256 + tid;
    const int row0 = b * L_ + c * CHL;

    float A_dn[16];
#pragma unroll
    for (int n = 0; n < 16; ++n) A_dn[n] = -__expf(A_log[(size_t)d * DS + n]);

    for (int k = 0; k < CHL; ++k) {
        size_t off = (size_t)(row0 + k) * DIN + d;
        sdt[k * 256 + tid] = (uint_t)dtfb[off] | ((uint_t)ucb[off] << 16);
    }
#pragma unroll
    for (int j = 0; j < 2; ++j) {
        int idx = tid + j * 256;
        int t = idx >> 4, n = idx & 15;
        sB[idx] = xdbl[(size_t)(row0 + t) * 96 + 64 + n];
    }
    __syncthreads();

    float q[16];
#pragma unroll
    for (int n = 0; n < 16; ++n) q[n] = 0.f;
    float s = 0.f;
    for (int k = 0; k < CHL; ++k) {
        uint_t pk = sdt[k * 256 + tid];
        float dtv = __uint_as_float(pk << 16);
        float uv  = __uint_as_float(pk & 0xffff0000u);
        float dtu = dtv * uv;
        s += dtv;
        f32x4 Bq[4];
#pragma unroll
        for (int j = 0; j < 4; ++j) Bq[j] = *(const f32x4*)(sB + k * 16 + j * 4);
#pragma unroll
        for (int n = 0; n < 16; ++n)
            q[n] = fmaf(__expf(dtv * A_dn[n]), q[n], dtu * Bq[n >> 2][n & 3]);
    }
    float* qp = bnd_q + ((size_t)(b * NCH + c) * DIN + d) * 16;
#pragma unroll
    for (int j = 0; j < 4; ++j)
        *(f32x4*)(qp + j * 4) = (f32x4){q[j * 4], q[j * 4 + 1], q[j * 4 + 2], q[j * 4 + 3]};
    bnd_s[(size_t)(b * NCH + c) * DIN + d] = s;
}

// S2: inline boundary combine from bnd -> rescan chunk -> gate -> store (in loop)
__global__ __launch_bounds__(256, 2) void scan_s2(const ushort_t* __restrict__ dtfb,
    const ushort_t* __restrict__ ucb_in, const float* __restrict__ xdbl,
    const ushort_t* __restrict__ xzb, const float* __restrict__ A_log,
    const float* __restrict__ Dvec, const float* __restrict__ bnd_q,
    const float* __restrict__ bnd_s, ushort_t* __restrict__ ucb_out)
{
    __shared__ uint_t sdt[CHL * 256];
    __shared__ float sBC[CHL * 32];
    const int tid = threadIdx.x;
    const int bx = blockIdx.x;
    const int dg = bx & 7, c = (bx >> 3) & 31, b = bx >> 8;
    const int d = dg * 256 + tid;
    const int row0 = b * L_ + c * CHL;
    const float Dd = Dvec[d];

    float A_dn[16];
#pragma unroll
    for (int n = 0; n < 16; ++n) A_dn[n] = -__expf(A_log[(size_t)d * DS + n]);

    for (int k = 0; k < CHL; ++k) {
        size_t off = (size_t)(row0 + k) * DIN + d;
        sdt[k * 256 + tid] = (uint_t)dtfb[off] | ((uint_t)ucb_in[off] << 16);
    }
#pragma unroll
    for (int j = 0; j < 4; ++j) {
        int idx = tid + j * 256;
        int t = idx >> 5, jj = idx & 31;
        sBC[idx] = xdbl[(size_t)(row0 + t) * 96 + 64 + (jj & 1) * 16 + (jj >> 1)];
    }

    // inline boundary combine: H before chunk c
    float h[16];
#pragma unroll
    for (int n = 0; n < 16; ++n) h[n] = 0.f;
    const size_t cb_base = (size_t)b * NCH * DIN + d;
    for (int cc = 0; cc < c; ++cc) {
        size_t idx = cb_base + (size_t)cc * DIN;
        float sv = bnd_s[idx];
        const float* qp = bnd_q + idx * 16;
        f32x4 qv[4];
#pragma unroll
        for (int j = 0; j < 4; ++j) qv[j] = *(const f32x4*)(qp + j * 4);
#pragma unroll
        for (int n = 0; n < 16; ++n)
            h[n] = fmaf(__expf(A_dn[n] * sv), h[n], qv[n >> 2][n & 3]);
    }
    __syncthreads();

    for (int k = 0; k < CHL; ++k) {
        uint_t pk = sdt[k * 256 + tid];
        float dtv = __uint_as_float(pk << 16);
        float uv  = __uint_as_float(pk & 0xffff0000u);
        float dtu = dtv * uv;
        float z = b2f(xzb[(size_t)(row0 + k) * (2 * DIN) + DIN + d]);
        float y = uv * Dd;
        f32x4 bcq[8];
#pragma unroll
        for (int j = 0; j < 8; ++j) bcq[j] = *(const f32x4*)(sBC + k * 32 + j * 4);
#pragma unroll
        for (int n = 0; n < 16; ++n) {
            float Bv = bcq[n >> 1][(n & 1) * 2];
            float Cv = bcq[n >> 1][(n & 1) * 2 + 1];
            h[n] = fmaf(__expf(dtv * A_dn[n]), h[n], dtu * Bv);
            y = fmaf(h[n], Cv, y);
        }
        y *= z * sigmoidf_(z);
        ucb_out[(size_t)(row0 + k) * DIN + d] = f2b(y);
    }
}

extern "C" void kernel_launch(void* const* d_in, const int* in_sizes, int n_in,
                              void* d_out, int out_size, void* d_ws, size_t ws_size,
                              hipStream_t stream)
{
    (void)in_sizes; (void)n_in; (void)out_size; (void)ws_size;
    const float* x      = (const float*)d_in[0];
    const float* W_in   = (const float*)d_in[1];
    const float* conv_w = (const float*)d_in[2];
    const float* conv_b = (const float*)d_in[3];
    const float* W_x    = (const float*)d_in[4];
    const float* W_dt   = (const float*)d_in[5];
    const float* b_dt   = (const float*)d_in[6];
    const float* A_log  = (const float*)d_in[7];
    const float* Dv     = (const float*)d_in[8];
    const float* W_out  = (const float*)d_in[9];
    float* out = (float*)d_out;

    // workspace layout
    float* xdbl    = (float*)d_ws;                       //   196,608 f32
    float* pws     = xdbl + 196608;                      // 1,572,864 f32
    float* bnd_q   = pws + 1572864;                      // 2,097,152 f32
    float* bnd_s   = bnd_q + 2097152;                    //   131,072 f32
    ushort_t* dtfb = (ushort_t*)(bnd_s + 131072);        // 4,194,304 u16
    ushort_t* xzb  = dtfb + 4194304;                     // 8,388,608
    ushort_t* ucb  = xzb + 8388608;                      // 4,194,304
    ushort_t* xdblb= ucb + 4194304;                      //   196,608
    ushort_t* xb   = xdblb + 196608;                     // 2,097,152 (x/h bf16)
    ushort_t* wib  = xb + 2097152;                       // 8,388,608
    ushort_t* wxb  = wib + 8388608;                      //   393,216
    ushort_t* wdb  = wxb + 393216;                       //   262,144
    ushort_t* wob  = wdb + 262144;                       // 4,194,304

    const int M = B_ * L_;
    const int NT = 2097152 + 8388608 + 393216 + 262144 + 4194304;
    f2b_all_k<<<(NT / 4) / 256, 256, 0, stream>>>(
        x, xb, 2097152, W_in, wib, 8388608, W_x, wxb, 393216,
        W_dt, wdb, 262144, W_out, wob, 4194304);

    for (int layer = 0; layer < 2; ++layer) {
        // xzb = bf16( h @ W_in^T )  [M, 4096]
        mgemm<3><<<dim3(4096 / 128, M / 128), 256, 0, stream>>>(
            xb, wib + (size_t)layer * 4194304, nullptr, xzb, nullptr,
            M, 2 * DIN, DM, DM, DM);
        // ucb = bf16(silu(conv(u) + b))
        conv8_k<<<(B_ * L_ * DIN / 8) / 256, 256, 0, stream>>>(
            xzb, conv_w + (size_t)layer * DIN * 4, conv_b + (size_t)layer * DIN, ucb);
        // xdbl = uc @ W_x^T  [M, 96]  (split-K x8 + reduce)
        mgemm_sk<<<dim3(1, M / 128, 8), 256, 0, stream>>>(
            ucb, wxb + (size_t)layer * 196608, pws, M, 96, DIN / 8, DIN, DIN);
        wxred_k<<<196608 / 256, 256, 0, stream>>>(pws, xdbl, xdblb);
        // dtfb = bf16(softplus(xdblb[:, :64] @ W_dt^T + b_dt))  [M, 2048]
        mgemm<2><<<dim3(2048 / 128, M / 128), 256, 0, stream>>>(
            xdblb, wdb + (size_t)layer * 131072, nullptr, dtfb,
            b_dt + (size_t)layer * DIN, M, DIN, DTR, 96, DTR);
        // chunk-parallel scan (states-in-registers, fused combine)
        const float* Al = A_log + (size_t)layer * DIN * DS;
        scan_s1<<<B_ * NCH * 8, 256, 0, stream>>>(dtfb, ucb, xdbl, Al, bnd_q, bnd_s);
        scan_s2<<<B_ * NCH * 8, 256, 0, stream>>>(dtfb, ucb, xdbl, xzb, Al,
            Dv + (size_t)layer * DIN, bnd_q, bnd_s, ucb);
        // out-proj (128x64 tiles): layer0 -> xb (bf16 h); layer1 -> out = acc + x
        if (layer == 0)
            mgemm_n64<3><<<dim3(1024 / 64, M / 128), 256, 0, stream>>>(
                ucb, wob + (size_t)layer * 2097152, nullptr, xb, nullptr,
                M, DM, DIN, DIN, DIN);
        else
            mgemm_n64<4><<<dim3(1024 / 64, M / 128), 256, 0, stream>>>(
                ucb, wob + (size_t)layer * 2097152, out, nullptr, x,
                M, DM, DIN, DIN, DIN);
    }
}